// Round 7
// baseline (12198.029 us; speedup 1.0000x reference)
//
#include <hip/hip_runtime.h>
#include <stdint.h>

#define S_LEN 4096
#define DIM   768
#define HID   384
#define GATES 1536   // 4*HID
#define NEV   1024
#define G_WG  12     // workgroups per direction for the recurrence

typedef unsigned short u16;
typedef short bf16x8 __attribute__((ext_vector_type(8)));
typedef float f32x4 __attribute__((ext_vector_type(4)));
typedef float f32x32 __attribute__((ext_vector_type(32)));

__device__ __forceinline__ u16 f2bf(float x) {
  union { float f; unsigned u; } c; c.f = x;
  unsigned r = c.u + 0x7fffu + ((c.u >> 16) & 1u);   // RNE
  return (u16)(r >> 16);
}
__device__ __forceinline__ float bf2f(u16 x) {
  union { unsigned u; float f; } c; c.u = ((unsigned)x) << 16;
  return c.f;
}
__device__ __forceinline__ float sigm(float x) { return 1.f / (1.f + __expf(-x)); }
__device__ __forceinline__ float tanh_fast(float x) { return 1.f - 2.f / (__expf(2.f * x) + 1.f); }

// ---------------- fp32 -> bf16 convert ----------------
__global__ void f2bf_kern(const float* __restrict__ in, u16* __restrict__ out, int n) {
  int i = blockIdx.x * blockDim.x + threadIdx.x;
  int st = gridDim.x * blockDim.x;
  for (; i < n; i += st) out[i] = f2bf(in[i]);
}

// ---------------- bf16 MFMA GEMM: C[M,N] = A[M,K] @ B[N,K]^T + bias ----------------
template <bool RELU, bool OUTBF16>
__launch_bounds__(256, 2)
__global__ void gemm_tn(const u16* __restrict__ A, const u16* __restrict__ B,
                        void* __restrict__ C, const float* __restrict__ biasA,
                        const float* __restrict__ biasB, int M, int N, int K) {
  __shared__ __align__(16) u16 As[128 * 40];
  __shared__ __align__(16) u16 Bs[128 * 40];
  int tid = threadIdx.x;
  int m0 = blockIdx.x * 128, n0 = blockIdx.y * 128;
  int wv = tid >> 6, lane = tid & 63;
  int wm = (wv >> 1) * 64, wn = (wv & 1) * 64;
  int l15 = lane & 15, q = lane >> 4;
  f32x4 acc[4][4] = {};
  int lrow = tid >> 1;
  int lseg = (tid & 1) * 16;

#pragma unroll 1
  for (int k0 = 0; k0 < K; k0 += 32) {
    const u16* ga = A + (size_t)(m0 + lrow) * K + k0 + lseg;
    const u16* gb = B + (size_t)(n0 + lrow) * K + k0 + lseg;
    int4 av0 = ((const int4*)ga)[0];
    int4 av1 = ((const int4*)ga)[1];
    int4 bv0 = ((const int4*)gb)[0];
    int4 bv1 = ((const int4*)gb)[1];
    __syncthreads();
    *(int4*)&As[lrow * 40 + lseg] = av0;
    *(int4*)&As[lrow * 40 + lseg + 8] = av1;
    *(int4*)&Bs[lrow * 40 + lseg] = bv0;
    *(int4*)&Bs[lrow * 40 + lseg + 8] = bv1;
    __syncthreads();
    bf16x8 af[4], bfr[4];
#pragma unroll
    for (int i = 0; i < 4; ++i) {
      af[i]  = *(bf16x8*)&As[(wm + i * 16 + l15) * 40 + q * 8];
      bfr[i] = *(bf16x8*)&Bs[(wn + i * 16 + l15) * 40 + q * 8];
    }
#pragma unroll
    for (int i = 0; i < 4; ++i)
#pragma unroll
      for (int j = 0; j < 4; ++j)
        acc[i][j] = __builtin_amdgcn_mfma_f32_16x16x32_bf16(af[i], bfr[j], acc[i][j], 0, 0, 0);
  }

#pragma unroll
  for (int i = 0; i < 4; ++i) {
#pragma unroll
    for (int j = 0; j < 4; ++j) {
      int gn = n0 + wn + j * 16 + l15;
      float bias = biasA ? biasA[gn] : 0.f;
      if (biasB) bias += biasB[gn];
#pragma unroll
      for (int v = 0; v < 4; ++v) {
        int gm = m0 + wm + i * 16 + q * 4 + v;
        float val = acc[i][j][v] + bias;
        if (RELU) val = fmaxf(val, 0.f);
        if (OUTBF16) ((u16*)C)[(size_t)gm * N + gn] = f2bf(val);
        else ((float*)C)[(size_t)gm * N + gn] = val;
      }
    }
  }
}

// ---------------- LSTM recurrence ----------------
// R6-proven structure (24 fixed blocks, agent-scope atomic handoff, self-flagging
// data: h+2 in (1,3), poison 0xAA = -3e-13 < 0.5). ONE change vs R6: weights live
// in SIX f32x32 SSA ext-vectors accessed ONLY with literal constant indices via a
// macro-unrolled FMA body. (R2/R6 failed because `float w[192]` indexed by a loop
// variable is never SROA-promoted -> alloca in scratch -> per-step L2 re-reads;
// VGPR_Count=116 both rounds proved it.)
#define K8(WV, o, gb)                                         \
  {                                                           \
    float4 hv0 = *(const float4*)(hh + (gb));                 \
    float4 hv1 = *(const float4*)(hh + (gb) + 4);             \
    a0 = fmaf(WV[(o) + 0], hv0.x, a0);                        \
    a1 = fmaf(WV[(o) + 1], hv0.y, a1);                        \
    a2 = fmaf(WV[(o) + 2], hv0.z, a2);                        \
    a3 = fmaf(WV[(o) + 3], hv0.w, a3);                        \
    a0 = fmaf(WV[(o) + 4], hv1.x, a0);                        \
    a1 = fmaf(WV[(o) + 5], hv1.y, a1);                        \
    a2 = fmaf(WV[(o) + 6], hv1.z, a2);                        \
    a3 = fmaf(WV[(o) + 7], hv1.w, a3);                        \
  }
#define K32(WV, gb) K8(WV, 0, gb) K8(WV, 8, (gb) + 8) K8(WV, 16, (gb) + 16) K8(WV, 24, (gb) + 24)

__launch_bounds__(256, 1)
__attribute__((amdgpu_waves_per_eu(1)))
__global__ void lstm_rec(const float* __restrict__ xw_f, const float* __restrict__ xw_b,
                         const float* __restrict__ Whh_f, const float* __restrict__ Whh_b,
                         float* __restrict__ tok) {
  int bx = blockIdx.x;
  int dir = bx / G_WG;
  int wg = bx % G_WG;
  const float* __restrict__ xw  = dir ? xw_b : xw_f;
  const float* __restrict__ Whh = dir ? Whh_b : Whh_f;
  int tid = threadIdx.x;
  int wvi = tid >> 6;          // wave 0..3
  int l = tid & 63;
  int half = l >> 5;           // k-half: cols [half*192, half*192+192)
  int r = l & 31;
  int g = r >> 3;              // gate i,f,g,o
  int uo = r & 7;              // unit offset within wave
  int unit = wg * 32 + wvi * 8 + uo;   // hidden unit [0,384)
  int grow = g * HID + unit;           // gate row [0,1536)

  // ---- weight slice as SSA vectors (constant-index access only) ----
  const f32x32* wp32 = (const f32x32*)(Whh + (size_t)grow * HID + half * 192);
  f32x32 W0 = wp32[0], W1 = wp32[1], W2 = wp32[2],
         W3 = wp32[3], W4 = wp32[4], W5 = wp32[5];

  __shared__ __align__(16) float hbuf[4][HID];   // per-wave private staging
  float* hb = hbuf[wvi];
  float cstate = 0.f;   // valid on lanes l<8

#pragma unroll 1
  for (int s = 0; s < S_LEN; ++s) {
    int t = dir ? (S_LEN - 1 - s) : s;
    float xwv = xw[(size_t)t * GATES + grow];   // independent of h; issued early

    if (s == 0) {
#pragma unroll
      for (int q = 0; q < 6; ++q) hb[6 * l + q] = 0.f;
    } else {
      int tp = dir ? (t + 1) : (t - 1);
      const unsigned long long* src64 =
          (const unsigned long long*)(tok + (size_t)tp * DIM + dir * HID + 6 * l);
      union { unsigned long long u; float2 f; } a, b, c;
      for (;;) {
        a.u = __hip_atomic_load(src64 + 0, __ATOMIC_RELAXED, __HIP_MEMORY_SCOPE_AGENT);
        b.u = __hip_atomic_load(src64 + 1, __ATOMIC_RELAXED, __HIP_MEMORY_SCOPE_AGENT);
        c.u = __hip_atomic_load(src64 + 2, __ATOMIC_RELAXED, __HIP_MEMORY_SCOPE_AGENT);
        if (a.f.x > 0.5f && a.f.y > 0.5f && b.f.x > 0.5f &&
            b.f.y > 0.5f && c.f.x > 0.5f && c.f.y > 0.5f) break;
      }
      hb[6 * l + 0] = a.f.x - 2.f; hb[6 * l + 1] = a.f.y - 2.f;
      hb[6 * l + 2] = b.f.x - 2.f; hb[6 * l + 3] = b.f.y - 2.f;
      hb[6 * l + 4] = c.f.x - 2.f; hb[6 * l + 5] = c.f.y - 2.f;
    }
    // same-wave DS ops are in-order: no barrier needed (per-wave private buffer).

    const float* hh = hb + half * 192;
    float a0 = 0.f, a1 = 0.f, a2 = 0.f, a3 = 0.f;
    K32(W0, 0)
    K32(W1, 32)
    K32(W2, 64)
    K32(W3, 96)
    K32(W4, 128)
    K32(W5, 160)
    float acc = (a0 + a1) + (a2 + a3);
    acc += __shfl_xor(acc, 32);
    acc += xwv;

    float gi = __shfl(acc, uo);
    float gf = __shfl(acc, 8 + uo);
    float gg = __shfl(acc, 16 + uo);
    float go = __shfl(acc, 24 + uo);
    if (l < 8) {
      float i_ = sigm(gi), f_ = sigm(gf), gv = tanh_fast(gg), o_ = sigm(go);
      cstate = f_ * cstate + i_ * gv;
      float h = o_ * tanh_fast(cstate);
      __hip_atomic_store(tok + (size_t)t * DIM + dir * HID + unit, h + 2.f,
                         __ATOMIC_RELAXED, __HIP_MEMORY_SCOPE_AGENT);
    }
  }
}

// ---------------- event mean-pooling (tok holds h+2; subtract after mean) ----------------
__global__ void event_emb_kern(const float* __restrict__ tok, const int* __restrict__ le,
                               u16* __restrict__ ev, float* __restrict__ out) {
  int e = blockIdx.x, tid = threadIdx.x;
  if (e == 0 && tid == 0) out[0] = 0.f;   // zero loss accumulator
  int st = le[3 * e], en = le[3 * e + 1];
  float inv = 1.f / (float)(en - st);
  for (int d = tid; d < DIM; d += 256) {
    float acc = 0.f;
    for (int t = st; t < en; ++t) acc += tok[(size_t)t * DIM + d];
    ev[(size_t)e * DIM + d] = f2bf(acc * inv - 2.f);
  }
}

// ---------------- scores + log_softmax + CE + loss ----------------
__global__ void scores_loss(const u16* __restrict__ hid, const float* __restrict__ W2,
                            const float* __restrict__ b2, const int* __restrict__ le,
                            float* __restrict__ out) {
  int tid = threadIdx.x;
  int e = blockIdx.x * 4 + (tid >> 6);
  int lane = tid & 63;
  float s0 = 0.f, s1 = 0.f;
  for (int d = lane; d < DIM; d += 64) {
    float h = bf2f(hid[(size_t)e * DIM + d]);
    s0 += h * W2[d];
    s1 += h * W2[DIM + d];
  }
#pragma unroll
  for (int off = 32; off > 0; off >>= 1) {
    s0 += __shfl_down(s0, off);
    s1 += __shfl_down(s1, off);
  }
  if (lane == 0) {
    s0 += b2[0]; s1 += b2[1];
    out[1 + 2 * e] = s0;
    out[2 + 2 * e] = s1;
    int label = le[3 * e + 2];
    float m = fmaxf(s0, s1);
    float lse = m + logf(__expf(s0 - m) + __expf(s1 - m));
    float ce = lse - (label ? s1 : s0);
    atomicAdd(&out[0], ce);
  }
}

extern "C" void kernel_launch(void* const* d_in, const int* in_sizes, int n_in,
                              void* d_out, int out_size, void* d_ws, size_t ws_size,
                              hipStream_t stream) {
  const float* temb  = (const float*)d_in[0];
  const int*   le    = (const int*)d_in[1];
  const float* Wih_f = (const float*)d_in[2];
  const float* Whh_f = (const float*)d_in[3];
  const float* bih_f = (const float*)d_in[4];
  const float* bhh_f = (const float*)d_in[5];
  const float* Wih_b = (const float*)d_in[6];
  const float* Whh_b = (const float*)d_in[7];
  const float* bih_b = (const float*)d_in[8];
  const float* bhh_b = (const float*)d_in[9];
  const float* W1    = (const float*)d_in[10];
  const float* b1    = (const float*)d_in[11];
  const float* W2    = (const float*)d_in[12];
  const float* b2    = (const float*)d_in[13];
  float* out = (float*)d_out;

  float* xw_f = (float*)d_ws;
  float* xw_b = xw_f + (size_t)S_LEN * GATES;
  float* tok  = xw_b + (size_t)S_LEN * GATES;
  u16* emb_bf  = (u16*)(tok + (size_t)S_LEN * DIM);
  u16* wihf_bf = emb_bf + (size_t)S_LEN * DIM;
  u16* wihb_bf = wihf_bf + (size_t)GATES * DIM;
  u16* w1_bf   = wihb_bf + (size_t)GATES * DIM;
  u16* ev_bf   = w1_bf + (size_t)DIM * DIM;
  u16* hid_bf  = ev_bf + (size_t)NEV * DIM;

  // 1. bf16 converts (tok keeps its 0xAA poison: it is the not-ready sentinel)
  f2bf_kern<<<768, 256, 0, stream>>>(temb, emb_bf, S_LEN * DIM);
  f2bf_kern<<<768, 256, 0, stream>>>(Wih_f, wihf_bf, GATES * DIM);
  f2bf_kern<<<768, 256, 0, stream>>>(Wih_b, wihb_bf, GATES * DIM);
  f2bf_kern<<<768, 256, 0, stream>>>(W1, w1_bf, DIM * DIM);

  // 2. xw = emb @ Wih^T + (bih + bhh), both directions
  gemm_tn<false, false><<<dim3(S_LEN / 128, GATES / 128), 256, 0, stream>>>(
      emb_bf, wihf_bf, xw_f, bih_f, bhh_f, S_LEN, GATES, DIM);
  gemm_tn<false, false><<<dim3(S_LEN / 128, GATES / 128), 256, 0, stream>>>(
      emb_bf, wihb_bf, xw_b, bih_b, bhh_b, S_LEN, GATES, DIM);

  // 3. bidirectional LSTM recurrence (fixed 24-WG grid, agent-scope handoff)
  lstm_rec<<<2 * G_WG, 256, 0, stream>>>(xw_f, xw_b, Whh_f, Whh_b, tok);

  // 4. event mean-pooling (also zeroes loss accumulator)
  event_emb_kern<<<NEV, 256, 0, stream>>>(tok, le, ev_bf, out);

  // 5. hidden = relu(ev @ W1^T + b1)
  gemm_tn<true, true><<<dim3(NEV / 128, DIM / 128), 256, 0, stream>>>(
      ev_bf, w1_bf, hid_bf, b1, nullptr, NEV, DIM, DIM);

  // 6. scores + log_softmax + weighted CE sum
  scores_loss<<<NEV / 4, 256, 0, stream>>>(hid_bf, W2, b2, le, out);
}

// Round 8
// 12073.116 us; speedup vs baseline: 1.0103x; 1.0103x over previous
//
#include <hip/hip_runtime.h>
#include <stdint.h>

#define S_LEN 4096
#define DIM   768
#define HID   384
#define GATES 1536   // 4*HID
#define NEV   1024
#define G_WG  12     // workgroups per direction for the recurrence

typedef unsigned short u16;
typedef short bf16x8 __attribute__((ext_vector_type(8)));
typedef float f32x4 __attribute__((ext_vector_type(4)));

__device__ __forceinline__ u16 f2bf(float x) {
  union { float f; unsigned u; } c; c.f = x;
  unsigned r = c.u + 0x7fffu + ((c.u >> 16) & 1u);   // RNE
  return (u16)(r >> 16);
}
__device__ __forceinline__ float bf2f(u16 x) {
  union { unsigned u; float f; } c; c.u = ((unsigned)x) << 16;
  return c.f;
}
__device__ __forceinline__ float sigm(float x) { return 1.f / (1.f + __expf(-x)); }
__device__ __forceinline__ float tanh_fast(float x) { return 1.f - 2.f / (__expf(2.f * x) + 1.f); }

// ---------------- fp32 -> bf16 convert ----------------
__global__ void f2bf_kern(const float* __restrict__ in, u16* __restrict__ out, int n) {
  int i = blockIdx.x * blockDim.x + threadIdx.x;
  int st = gridDim.x * blockDim.x;
  for (; i < n; i += st) out[i] = f2bf(in[i]);
}

// ---------------- bf16 MFMA GEMM: C[M,N] = A[M,K] @ B[N,K]^T + bias ----------------
template <bool RELU, bool OUTBF16>
__launch_bounds__(256, 2)
__global__ void gemm_tn(const u16* __restrict__ A, const u16* __restrict__ B,
                        void* __restrict__ C, const float* __restrict__ biasA,
                        const float* __restrict__ biasB, int M, int N, int K) {
  __shared__ __align__(16) u16 As[128 * 40];
  __shared__ __align__(16) u16 Bs[128 * 40];
  int tid = threadIdx.x;
  int m0 = blockIdx.x * 128, n0 = blockIdx.y * 128;
  int wv = tid >> 6, lane = tid & 63;
  int wm = (wv >> 1) * 64, wn = (wv & 1) * 64;
  int l15 = lane & 15, q = lane >> 4;
  f32x4 acc[4][4] = {};
  int lrow = tid >> 1;
  int lseg = (tid & 1) * 16;

#pragma unroll 1
  for (int k0 = 0; k0 < K; k0 += 32) {
    const u16* ga = A + (size_t)(m0 + lrow) * K + k0 + lseg;
    const u16* gb = B + (size_t)(n0 + lrow) * K + k0 + lseg;
    int4 av0 = ((const int4*)ga)[0];
    int4 av1 = ((const int4*)ga)[1];
    int4 bv0 = ((const int4*)gb)[0];
    int4 bv1 = ((const int4*)gb)[1];
    __syncthreads();
    *(int4*)&As[lrow * 40 + lseg] = av0;
    *(int4*)&As[lrow * 40 + lseg + 8] = av1;
    *(int4*)&Bs[lrow * 40 + lseg] = bv0;
    *(int4*)&Bs[lrow * 40 + lseg + 8] = bv1;
    __syncthreads();
    bf16x8 af[4], bfr[4];
#pragma unroll
    for (int i = 0; i < 4; ++i) {
      af[i]  = *(bf16x8*)&As[(wm + i * 16 + l15) * 40 + q * 8];
      bfr[i] = *(bf16x8*)&Bs[(wn + i * 16 + l15) * 40 + q * 8];
    }
#pragma unroll
    for (int i = 0; i < 4; ++i)
#pragma unroll
      for (int j = 0; j < 4; ++j)
        acc[i][j] = __builtin_amdgcn_mfma_f32_16x16x32_bf16(af[i], bfr[j], acc[i][j], 0, 0, 0);
  }

#pragma unroll
  for (int i = 0; i < 4; ++i) {
#pragma unroll
    for (int j = 0; j < 4; ++j) {
      int gn = n0 + wn + j * 16 + l15;
      float bias = biasA ? biasA[gn] : 0.f;
      if (biasB) bias += biasB[gn];
#pragma unroll
      for (int v = 0; v < 4; ++v) {
        int gm = m0 + wm + i * 16 + q * 4 + v;
        float val = acc[i][j][v] + bias;
        if (RELU) val = fmaxf(val, 0.f);
        if (OUTBF16) ((u16*)C)[(size_t)gm * N + gn] = f2bf(val);
        else ((float*)C)[(size_t)gm * N + gn] = val;
      }
    }
  }
}

// ---------------- LSTM recurrence ----------------
// R7-proven structure (24 fixed blocks, agent-scope atomic handoff, self-flagging
// data: h+2 in (1,3), poison 0xAA = -3e-13 < 0.5). ONE change vs R7: the 48 f32x4
// weight chunks are each passed through asm volatile identity AFTER loading.
// R7 post-mortem: plain loads from const __restrict__ are trivially
// rematerializable, so RA sank them back into the loop (VGPR=116, ~2400cyc/step of
// exposed L2 latency at ~10 loads in flight). The volatile asm result cannot be
// rematerialized; with a 512-VGPR budget (waves_per_eu 1) keep-live beats spill.
#define WDECL(i) f32x4 W##i = wp4[i]; asm volatile("" : "+v"(W##i));
#define WFMA(i)                                               \
  {                                                           \
    f32x4 hv = *(const f32x4*)(hh + 4 * (i));                 \
    a0 = fmaf(W##i[0], hv[0], a0);                            \
    a1 = fmaf(W##i[1], hv[1], a1);                            \
    a2 = fmaf(W##i[2], hv[2], a2);                            \
    a3 = fmaf(W##i[3], hv[3], a3);                            \
  }

__launch_bounds__(256, 1)
__attribute__((amdgpu_waves_per_eu(1)))
__global__ void lstm_rec(const float* __restrict__ xw_f, const float* __restrict__ xw_b,
                         const float* __restrict__ Whh_f, const float* __restrict__ Whh_b,
                         float* __restrict__ tok) {
  int bx = blockIdx.x;
  int dir = bx / G_WG;
  int wg = bx % G_WG;
  const float* __restrict__ xw  = dir ? xw_b : xw_f;
  const float* __restrict__ Whh = dir ? Whh_b : Whh_f;
  int tid = threadIdx.x;
  int wvi = tid >> 6;          // wave 0..3
  int l = tid & 63;
  int half = l >> 5;           // k-half: cols [half*192, half*192+192)
  int r = l & 31;
  int g = r >> 3;              // gate i,f,g,o
  int uo = r & 7;              // unit offset within wave
  int unit = wg * 32 + wvi * 8 + uo;   // hidden unit [0,384)
  int grow = g * HID + unit;           // gate row [0,1536)

  // ---- weight slice: 48 named f32x4 SSA values, pinned via opaque asm ----
  const f32x4* wp4 = (const f32x4*)(Whh + (size_t)grow * HID + half * 192);
  WDECL(0)  WDECL(1)  WDECL(2)  WDECL(3)  WDECL(4)  WDECL(5)  WDECL(6)  WDECL(7)
  WDECL(8)  WDECL(9)  WDECL(10) WDECL(11) WDECL(12) WDECL(13) WDECL(14) WDECL(15)
  WDECL(16) WDECL(17) WDECL(18) WDECL(19) WDECL(20) WDECL(21) WDECL(22) WDECL(23)
  WDECL(24) WDECL(25) WDECL(26) WDECL(27) WDECL(28) WDECL(29) WDECL(30) WDECL(31)
  WDECL(32) WDECL(33) WDECL(34) WDECL(35) WDECL(36) WDECL(37) WDECL(38) WDECL(39)
  WDECL(40) WDECL(41) WDECL(42) WDECL(43) WDECL(44) WDECL(45) WDECL(46) WDECL(47)

  __shared__ __align__(16) float hbuf[4][HID];   // per-wave private staging
  float* hb = hbuf[wvi];
  float cstate = 0.f;   // valid on lanes l<8

#pragma unroll 1
  for (int s = 0; s < S_LEN; ++s) {
    int t = dir ? (S_LEN - 1 - s) : s;
    float xwv = xw[(size_t)t * GATES + grow];   // independent of h; issued early

    if (s == 0) {
#pragma unroll
      for (int q = 0; q < 6; ++q) hb[6 * l + q] = 0.f;
    } else {
      int tp = dir ? (t + 1) : (t - 1);
      const unsigned long long* src64 =
          (const unsigned long long*)(tok + (size_t)tp * DIM + dir * HID + 6 * l);
      union { unsigned long long u; float2 f; } a, b, c;
      for (;;) {
        a.u = __hip_atomic_load(src64 + 0, __ATOMIC_RELAXED, __HIP_MEMORY_SCOPE_AGENT);
        b.u = __hip_atomic_load(src64 + 1, __ATOMIC_RELAXED, __HIP_MEMORY_SCOPE_AGENT);
        c.u = __hip_atomic_load(src64 + 2, __ATOMIC_RELAXED, __HIP_MEMORY_SCOPE_AGENT);
        if (a.f.x > 0.5f && a.f.y > 0.5f && b.f.x > 0.5f &&
            b.f.y > 0.5f && c.f.x > 0.5f && c.f.y > 0.5f) break;
      }
      hb[6 * l + 0] = a.f.x - 2.f; hb[6 * l + 1] = a.f.y - 2.f;
      hb[6 * l + 2] = b.f.x - 2.f; hb[6 * l + 3] = b.f.y - 2.f;
      hb[6 * l + 4] = c.f.x - 2.f; hb[6 * l + 5] = c.f.y - 2.f;
    }
    // same-wave DS ops are in-order: no barrier needed (per-wave private buffer).

    const float* hh = hb + half * 192;
    float a0 = 0.f, a1 = 0.f, a2 = 0.f, a3 = 0.f;
    WFMA(0)  WFMA(1)  WFMA(2)  WFMA(3)  WFMA(4)  WFMA(5)  WFMA(6)  WFMA(7)
    WFMA(8)  WFMA(9)  WFMA(10) WFMA(11) WFMA(12) WFMA(13) WFMA(14) WFMA(15)
    WFMA(16) WFMA(17) WFMA(18) WFMA(19) WFMA(20) WFMA(21) WFMA(22) WFMA(23)
    WFMA(24) WFMA(25) WFMA(26) WFMA(27) WFMA(28) WFMA(29) WFMA(30) WFMA(31)
    WFMA(32) WFMA(33) WFMA(34) WFMA(35) WFMA(36) WFMA(37) WFMA(38) WFMA(39)
    WFMA(40) WFMA(41) WFMA(42) WFMA(43) WFMA(44) WFMA(45) WFMA(46) WFMA(47)
    float acc = (a0 + a1) + (a2 + a3);
    acc += __shfl_xor(acc, 32);
    acc += xwv;

    float gi = __shfl(acc, uo);
    float gf = __shfl(acc, 8 + uo);
    float gg = __shfl(acc, 16 + uo);
    float go = __shfl(acc, 24 + uo);
    if (l < 8) {
      float i_ = sigm(gi), f_ = sigm(gf), gv = tanh_fast(gg), o_ = sigm(go);
      cstate = f_ * cstate + i_ * gv;
      float h = o_ * tanh_fast(cstate);
      __hip_atomic_store(tok + (size_t)t * DIM + dir * HID + unit, h + 2.f,
                         __ATOMIC_RELAXED, __HIP_MEMORY_SCOPE_AGENT);
    }
  }
}

// ---------------- event mean-pooling (tok holds h+2; subtract after mean) ----------------
__global__ void event_emb_kern(const float* __restrict__ tok, const int* __restrict__ le,
                               u16* __restrict__ ev, float* __restrict__ out) {
  int e = blockIdx.x, tid = threadIdx.x;
  if (e == 0 && tid == 0) out[0] = 0.f;   // zero loss accumulator
  int st = le[3 * e], en = le[3 * e + 1];
  float inv = 1.f / (float)(en - st);
  for (int d = tid; d < DIM; d += 256) {
    float acc = 0.f;
    for (int t = st; t < en; ++t) acc += tok[(size_t)t * DIM + d];
    ev[(size_t)e * DIM + d] = f2bf(acc * inv - 2.f);
  }
}

// ---------------- scores + log_softmax + CE + loss ----------------
__global__ void scores_loss(const u16* __restrict__ hid, const float* __restrict__ W2,
                            const float* __restrict__ b2, const int* __restrict__ le,
                            float* __restrict__ out) {
  int tid = threadIdx.x;
  int e = blockIdx.x * 4 + (tid >> 6);
  int lane = tid & 63;
  float s0 = 0.f, s1 = 0.f;
  for (int d = lane; d < DIM; d += 64) {
    float h = bf2f(hid[(size_t)e * DIM + d]);
    s0 += h * W2[d];
    s1 += h * W2[DIM + d];
  }
#pragma unroll
  for (int off = 32; off > 0; off >>= 1) {
    s0 += __shfl_down(s0, off);
    s1 += __shfl_down(s1, off);
  }
  if (lane == 0) {
    s0 += b2[0]; s1 += b2[1];
    out[1 + 2 * e] = s0;
    out[2 + 2 * e] = s1;
    int label = le[3 * e + 2];
    float m = fmaxf(s0, s1);
    float lse = m + logf(__expf(s0 - m) + __expf(s1 - m));
    float ce = lse - (label ? s1 : s0);
    atomicAdd(&out[0], ce);
  }
}

extern "C" void kernel_launch(void* const* d_in, const int* in_sizes, int n_in,
                              void* d_out, int out_size, void* d_ws, size_t ws_size,
                              hipStream_t stream) {
  const float* temb  = (const float*)d_in[0];
  const int*   le    = (const int*)d_in[1];
  const float* Wih_f = (const float*)d_in[2];
  const float* Whh_f = (const float*)d_in[3];
  const float* bih_f = (const float*)d_in[4];
  const float* bhh_f = (const float*)d_in[5];
  const float* Wih_b = (const float*)d_in[6];
  const float* Whh_b = (const float*)d_in[7];
  const float* bih_b = (const float*)d_in[8];
  const float* bhh_b = (const float*)d_in[9];
  const float* W1    = (const float*)d_in[10];
  const float* b1    = (const float*)d_in[11];
  const float* W2    = (const float*)d_in[12];
  const float* b2    = (const float*)d_in[13];
  float* out = (float*)d_out;

  float* xw_f = (float*)d_ws;
  float* xw_b = xw_f + (size_t)S_LEN * GATES;
  float* tok  = xw_b + (size_t)S_LEN * GATES;
  u16* emb_bf  = (u16*)(tok + (size_t)S_LEN * DIM);
  u16* wihf_bf = emb_bf + (size_t)S_LEN * DIM;
  u16* wihb_bf = wihf_bf + (size_t)GATES * DIM;
  u16* w1_bf   = wihb_bf + (size_t)GATES * DIM;
  u16* ev_bf   = w1_bf + (size_t)DIM * DIM;
  u16* hid_bf  = ev_bf + (size_t)NEV * DIM;

  // 1. bf16 converts (tok keeps its 0xAA poison: it is the not-ready sentinel)
  f2bf_kern<<<768, 256, 0, stream>>>(temb, emb_bf, S_LEN * DIM);
  f2bf_kern<<<768, 256, 0, stream>>>(Wih_f, wihf_bf, GATES * DIM);
  f2bf_kern<<<768, 256, 0, stream>>>(Wih_b, wihb_bf, GATES * DIM);
  f2bf_kern<<<768, 256, 0, stream>>>(W1, w1_bf, DIM * DIM);

  // 2. xw = emb @ Wih^T + (bih + bhh), both directions
  gemm_tn<false, false><<<dim3(S_LEN / 128, GATES / 128), 256, 0, stream>>>(
      emb_bf, wihf_bf, xw_f, bih_f, bhh_f, S_LEN, GATES, DIM);
  gemm_tn<false, false><<<dim3(S_LEN / 128, GATES / 128), 256, 0, stream>>>(
      emb_bf, wihb_bf, xw_b, bih_b, bhh_b, S_LEN, GATES, DIM);

  // 3. bidirectional LSTM recurrence (fixed 24-WG grid, agent-scope handoff)
  lstm_rec<<<2 * G_WG, 256, 0, stream>>>(xw_f, xw_b, Whh_f, Whh_b, tok);

  // 4. event mean-pooling (also zeroes loss accumulator)
  event_emb_kern<<<NEV, 256, 0, stream>>>(tok, le, ev_bf, out);

  // 5. hidden = relu(ev @ W1^T + b1)
  gemm_tn<true, true><<<dim3(NEV / 128, DIM / 128), 256, 0, stream>>>(
      ev_bf, w1_bf, hid_bf, b1, nullptr, NEV, DIM, DIM);

  // 6. scores + log_softmax + weighted CE sum
  scores_loss<<<NEV / 4, 256, 0, stream>>>(hid_bf, W2, b2, le, out);
}